// Round 5
// baseline (1046.407 us; speedup 1.0000x reference)
//
#include <hip/hip_runtime.h>
#include <hip/hip_bf16.h>
#include <stdint.h>

#define NE 8
#define NTOK 8192        // B*T
#define HD 1024
#define FD 4096
#define NSLOT (NTOK * 2)

typedef __attribute__((ext_vector_type(4))) float floatx4;
typedef __attribute__((ext_vector_type(8))) __bf16 bf16x8;
typedef __attribute__((ext_vector_type(8))) unsigned short ushortx8;

__device__ __forceinline__ unsigned short f2bf(float f) {
    union { float f; unsigned u; } v; v.f = f;
    unsigned r = v.u + 0x7FFFu + ((v.u >> 16) & 1u);   // RNE
    return (unsigned short)(r >> 16);
}

__device__ __forceinline__ void gload_lds16(const unsigned short* g, unsigned short* l) {
    __builtin_amdgcn_global_load_lds(
        (const __attribute__((address_space(1))) void*)g,
        (__attribute__((address_space(3))) void*)l,
        16, 0, 0);
}

// ------------- transpose + cast: w[e][r][c] (fp32) -> wt[e][c][r] (bf16) -------------
__global__ void transpose_cast_kernel(const float* __restrict__ w, unsigned short* __restrict__ wt,
                                      int rows, int cols) {
    __shared__ unsigned short tile[64][66];
    int e = blockIdx.z;
    int r0 = blockIdx.y * 64;
    int c0 = blockIdx.x * 64;
    const float* ws = w + (size_t)e * rows * cols;
    unsigned short* wd = wt + (size_t)e * rows * cols;
    int tid = threadIdx.x;   // 256
#pragma unroll
    for (int j = 0; j < 4; j++) {
        int idx = j * 256 + tid;
        int r = idx >> 4;
        int c4 = (idx & 15) * 4;
        float4 v = *(const float4*)(ws + (size_t)(r0 + r) * cols + c0 + c4);
        ushort2 lo, hi;
        lo.x = f2bf(v.x); lo.y = f2bf(v.y);
        hi.x = f2bf(v.z); hi.y = f2bf(v.w);
        *(ushort2*)&tile[r][c4]     = lo;
        *(ushort2*)&tile[r][c4 + 2] = hi;
    }
    __syncthreads();
#pragma unroll
    for (int j = 0; j < 2; j++) {
        int idx = j * 256 + tid;
        int c = idx >> 3;
        int r8 = (idx & 7) * 8;
        ushortx8 o;
#pragma unroll
        for (int k = 0; k < 8; k++) o[k] = tile[r8 + k][c];
        *(ushortx8*)(wd + (size_t)(c0 + c) * rows + r0 + r8) = o;
    }
}

// ---------------- router: logits, top-2 softmax, slot lists, x->bf16 cast ----------------
__global__ void router_kernel(const float* __restrict__ x, const float* __restrict__ gw,
                              float* __restrict__ logits, int* __restrict__ counts,
                              int* __restrict__ perm, float* __restrict__ wts,
                              unsigned short* __restrict__ xb) {
    int lane = threadIdx.x & 63;
    int t = blockIdx.x * 4 + (threadIdx.x >> 6);   // one wave per token
    const float* xr = x + (size_t)t * HD;
    unsigned short* xbr = xb + (size_t)t * HD;
    float a0=0,a1=0,a2=0,a3=0,a4=0,a5=0,a6=0,a7=0;
    for (int c = lane; c < HD; c += 64) {
        float xv = xr[c];
        xbr[c] = f2bf(xv);
        const float4* g = (const float4*)(gw + (size_t)c * NE);
        float4 g0 = g[0], g1 = g[1];
        a0 += xv * g0.x; a1 += xv * g0.y; a2 += xv * g0.z; a3 += xv * g0.w;
        a4 += xv * g1.x; a5 += xv * g1.y; a6 += xv * g1.z; a7 += xv * g1.w;
    }
#pragma unroll
    for (int off = 32; off > 0; off >>= 1) {
        a0 += __shfl_xor(a0, off); a1 += __shfl_xor(a1, off);
        a2 += __shfl_xor(a2, off); a3 += __shfl_xor(a3, off);
        a4 += __shfl_xor(a4, off); a5 += __shfl_xor(a5, off);
        a6 += __shfl_xor(a6, off); a7 += __shfl_xor(a7, off);
    }
    if (lane == 0) {
        float l[8] = {a0,a1,a2,a3,a4,a5,a6,a7};
        float4 s0 = make_float4(a0,a1,a2,a3);
        float4 s1 = make_float4(a4,a5,a6,a7);
        ((float4*)(logits + (size_t)t * NE))[0] = s0;
        ((float4*)(logits + (size_t)t * NE))[1] = s1;
        int e0 = 0; float v0 = l[0];
#pragma unroll
        for (int e = 1; e < 8; e++) if (l[e] > v0) { v0 = l[e]; e0 = e; }
        int e1 = -1; float v1 = -3.4e38f;
#pragma unroll
        for (int e = 0; e < 8; e++) if (e != e0 && l[e] > v1) { v1 = l[e]; e1 = e; }
        float ex = __expf(v1 - v0);
        float dn = 1.f + ex;
        wts[2*t]   = 1.f / dn;
        wts[2*t+1] = ex / dn;
        int p0 = atomicAdd(&counts[e0], 1);
        perm[e0 * NTOK + p0] = 2 * t;
        int p1 = atomicAdd(&counts[e1], 1);
        perm[e1 * NTOK + p1] = 2 * t + 1;
    }
}

// ---------------- gathered GEMM: 128x256 tile, 512 threads, single-buffer ----------------
// C[M x NTOT] = gather(A)[M x KTOT] * Bt[e]^T, Bt stored [NTOT x KTOT] (B^T).
// Grid (round-1 order, proven): x = n-tile (fast, 256-wide), y = e*64+mtile.
// Widening N-tile 128->256 halves the A-panel re-fetch multiplicity (the
// dominant L2-miss stream per rounds 1-4) while preserving round-1's
// per-XCD B-panel L2 reuse (x remains the fast dim).
// 8 waves, each computes a 64x64 quadrant -> acc 4x4 (64 AGPRs), ~124 regs.
// G1: A row = xb[slot>>1], epilogue relu->bf16 into h[slot].
// !G1: A row = h[slot], epilogue atomicAdd(out[slot>>1], w[slot]*acc).
template<int KTOT, int NTOT, bool G1>
__global__ __launch_bounds__(512, 4)
void moe_gemm(const unsigned short* __restrict__ A,
              const unsigned short* __restrict__ Bt,
              unsigned short* __restrict__ Hout,
              float* __restrict__ Out,
              const int* __restrict__ counts,
              const int* __restrict__ perm,
              const float* __restrict__ wts) {
    int e = blockIdx.y >> 6;
    int mtile = blockIdx.y & 63;
    int cnt = counts[e];
    if (mtile * 128 >= cnt) return;
    int n0 = blockIdx.x * 256;

    __shared__ unsigned short lds[128 * 64 + 256 * 64];   // A 16 KiB | B 32 KiB
    __shared__ int slotLds[128];
    __shared__ float wLds[128];

    int tid = threadIdx.x;
    int lane = tid & 63;
    int wv = tid >> 6;          // 0..7
    const int* permE = perm + e * NTOK + mtile * 128;

    if (tid < 128) {
        int s = (mtile * 128 + tid < cnt) ? permE[tid] : -1;
        slotLds[tid] = s;
        if (!G1) wLds[tid] = (s >= 0) ? wts[s] : 0.f;
    }

    // staging: thread handles row r = it*64 + (tid>>3), phys chunk tid&7.
    const unsigned short* aRow[2];
    const unsigned short* bRow[4];
#pragma unroll
    for (int it = 0; it < 2; it++) {
        int r = it * 64 + (tid >> 3);
        int s = (mtile * 128 + r < cnt) ? permE[r] : permE[0];   // clamp to a valid row
        size_t arow = G1 ? (size_t)(s >> 1) : (size_t)s;
        aRow[it] = A + arow * KTOT;
    }
#pragma unroll
    for (int it = 0; it < 4; it++) {
        int r = it * 64 + (tid >> 3);
        bRow[it] = Bt + ((size_t)e * NTOT + n0 + r) * KTOT;
    }
    // XOR swizzle: logical k-chunk j of row r lives at physical chunk j^(r&7).
    int koff = ((tid & 7) ^ ((tid >> 3) & 7)) * 8;   // elements
    unsigned short* ldsA = lds;
    unsigned short* ldsB = lds + 128 * 64;
    int wbase = wv * 512;                            // wave-uniform LDS base (elems)

    floatx4 acc[4][4];
    floatx4 zero = {0.f, 0.f, 0.f, 0.f};
#pragma unroll
    for (int i = 0; i < 4; i++)
#pragma unroll
        for (int j = 0; j < 4; j++) acc[i][j] = zero;

    int m = lane & 15, quad = lane >> 4;
    int rA = (wv >> 2) * 64 + m;     // + mi*16  (rows 0..127)
    int rB = (wv & 3) * 64 + m;      // + ni*16  (rows 0..255)
    int xs = m & 7;                  // fragment-read swizzle (row&7 == m&7)

    for (int k0 = 0; k0 < KTOT; k0 += 64) {
#pragma unroll
        for (int it = 0; it < 2; it++)
            gload_lds16(aRow[it] + k0 + koff, ldsA + it * 4096 + wbase);
#pragma unroll
        for (int it = 0; it < 4; it++)
            gload_lds16(bRow[it] + k0 + koff, ldsB + it * 4096 + wbase);
        __builtin_amdgcn_s_waitcnt(0);
        __syncthreads();
#pragma unroll
        for (int kk = 0; kk < 2; kk++) {
            bf16x8 af[4], bfr[4];
#pragma unroll
            for (int mi = 0; mi < 4; mi++)
                af[mi] = *(const bf16x8*)(ldsA + (((rA + mi * 16) * 8 + ((kk * 4 + quad) ^ xs)) * 8));
#pragma unroll
            for (int ni = 0; ni < 4; ni++)
                bfr[ni] = *(const bf16x8*)(ldsB + (((rB + ni * 16) * 8 + ((kk * 4 + quad) ^ xs)) * 8));
#pragma unroll
            for (int mi = 0; mi < 4; mi++)
#pragma unroll
                for (int ni = 0; ni < 4; ni++)
                    acc[mi][ni] = __builtin_amdgcn_mfma_f32_16x16x32_bf16(af[mi], bfr[ni], acc[mi][ni], 0, 0, 0);
        }
        __syncthreads();
    }

    // epilogue: C/D layout col = lane&15, row = quad*4 + reg
    int colb = (wv & 3) * 64 + m;          // + ni*16
    int rb = (wv >> 2) * 64 + quad * 4;    // + mi*16 + reg
#pragma unroll
    for (int mi = 0; mi < 4; mi++) {
#pragma unroll
        for (int reg = 0; reg < 4; reg++) {
            int rl = rb + mi * 16 + reg;
            int s = slotLds[rl];
            if (s < 0) continue;
            if (G1) {
                unsigned short* hr = Hout + (size_t)s * NTOT + n0 + colb;
#pragma unroll
                for (int ni = 0; ni < 4; ni++) {
                    float v = acc[mi][ni][reg];
                    hr[ni * 16] = f2bf(v > 0.f ? v : 0.f);
                }
            } else {
                float w = wLds[rl];
                float* orow = Out + (size_t)(s >> 1) * NTOT + n0 + colb;
#pragma unroll
                for (int ni = 0; ni < 4; ni++)
                    atomicAdd(&orow[ni * 16], w * acc[mi][ni][reg]);
            }
        }
    }
}

extern "C" void kernel_launch(void* const* d_in, const int* in_sizes, int n_in,
                              void* d_out, int out_size, void* d_ws, size_t ws_size,
                              hipStream_t stream) {
    (void)in_sizes; (void)n_in; (void)out_size;
    const float* x  = (const float*)d_in[0];
    const float* gw = (const float*)d_in[1];
    const float* w1 = (const float*)d_in[2];
    const float* w2 = (const float*)d_in[3];
    float* out = (float*)d_out;
    float* logits = out + (size_t)NTOK * HD;

    char* ws = (char*)d_ws;
    int*   counts = (int*)ws;                              // 32 B
    int*   perm   = (int*)(ws + 256);                      // 8*8192*4 = 256 KiB
    float* wts    = (float*)(ws + 256 + 262144);           // 64 KiB
    unsigned short* xb    = (unsigned short*)(ws + 393216);            // 16 MiB
    unsigned short* wtbuf = xb + (size_t)NTOK * HD;                    // 64 MiB (w1t, then w2t)
    unsigned short* h     = wtbuf + (size_t)NE * HD * FD;              // 128 MiB
    size_t needed = 393216 + (size_t)NTOK*HD*2 + (size_t)NE*HD*FD*2 + (size_t)NSLOT*FD*2;
    if (ws_size < needed) return;   // workspace too small — cannot run

    hipMemsetAsync(counts, 0, 32, stream);
    hipMemsetAsync(out, 0, (size_t)NTOK * HD * sizeof(float), stream);

    // w1: [E][H][F] -> w1t [E][F][H]  (rows=H, cols=F)
    transpose_cast_kernel<<<dim3(FD / 64, HD / 64, NE), 256, 0, stream>>>(w1, wtbuf, HD, FD);
    router_kernel<<<NTOK / 4, 256, 0, stream>>>(x, gw, logits, counts, perm, wts, xb);
    // h[s] = relu(xb[token] @ w1[e]) : K=1024, N=4096 — grid x=n-tile (fast), y=emt
    moe_gemm<HD, FD, true><<<dim3(FD / 256, NE * 64), 512, 0, stream>>>(
        xb, wtbuf, h, nullptr, counts, perm, wts);
    // w2: [E][F][H] -> w2t [E][H][F] (reuse wtbuf; stream order serializes after gemm1)
    transpose_cast_kernel<<<dim3(HD / 64, FD / 64, NE), 256, 0, stream>>>(w2, wtbuf, FD, HD);
    // out[t] += w[s] * (h[s] @ w2[e]) : K=4096, N=1024 — grid x=n-tile (fast), y=emt
    moe_gemm<FD, HD, false><<<dim3(HD / 256, NE * 64), 512, 0, stream>>>(
        h, wtbuf, nullptr, out, counts, perm, wts);
}

// Round 6
// 764.413 us; speedup vs baseline: 1.3689x; 1.3689x over previous
//
#include <hip/hip_runtime.h>
#include <hip/hip_bf16.h>
#include <stdint.h>

#define NE 8
#define NTOK 8192        // B*T
#define HD 1024
#define FD 4096
#define NSLOT (NTOK * 2)

typedef __attribute__((ext_vector_type(4))) float floatx4;
typedef __attribute__((ext_vector_type(8))) __bf16 bf16x8;
typedef __attribute__((ext_vector_type(8))) unsigned short ushortx8;

__device__ __forceinline__ unsigned short f2bf(float f) {
    union { float f; unsigned u; } v; v.f = f;
    unsigned r = v.u + 0x7FFFu + ((v.u >> 16) & 1u);   // RNE
    return (unsigned short)(r >> 16);
}

__device__ __forceinline__ void gload_lds16(const unsigned short* g, unsigned short* l) {
    __builtin_amdgcn_global_load_lds(
        (const __attribute__((address_space(1))) void*)g,
        (__attribute__((address_space(3))) void*)l,
        16, 0, 0);
}

// ------------- transpose + cast: w[e][r][c] (fp32) -> wt[e][c][r] (bf16) -------------
__global__ void transpose_cast_kernel(const float* __restrict__ w, unsigned short* __restrict__ wt,
                                      int rows, int cols) {
    __shared__ unsigned short tile[64][66];
    int e = blockIdx.z;
    int r0 = blockIdx.y * 64;
    int c0 = blockIdx.x * 64;
    const float* ws = w + (size_t)e * rows * cols;
    unsigned short* wd = wt + (size_t)e * rows * cols;
    int tid = threadIdx.x;   // 256
#pragma unroll
    for (int j = 0; j < 4; j++) {
        int idx = j * 256 + tid;
        int r = idx >> 4;
        int c4 = (idx & 15) * 4;
        float4 v = *(const float4*)(ws + (size_t)(r0 + r) * cols + c0 + c4);
        ushort2 lo, hi;
        lo.x = f2bf(v.x); lo.y = f2bf(v.y);
        hi.x = f2bf(v.z); hi.y = f2bf(v.w);
        *(ushort2*)&tile[r][c4]     = lo;
        *(ushort2*)&tile[r][c4 + 2] = hi;
    }
    __syncthreads();
#pragma unroll
    for (int j = 0; j < 2; j++) {
        int idx = j * 256 + tid;
        int c = idx >> 3;
        int r8 = (idx & 7) * 8;
        ushortx8 o;
#pragma unroll
        for (int k = 0; k < 8; k++) o[k] = tile[r8 + k][c];
        *(ushortx8*)(wd + (size_t)(c0 + c) * rows + r0 + r8) = o;
    }
}

// -------- router phase A: logits, top-2 softmax, eid/wts per slot, x->bf16 cast --------
// NO atomics (the old single-phase router serialized 16K same-cache-line atomicAdds).
__global__ void router_kernel(const float* __restrict__ x, const float* __restrict__ gw,
                              float* __restrict__ logits, int* __restrict__ eid,
                              float* __restrict__ wts, unsigned short* __restrict__ xb) {
    int lane = threadIdx.x & 63;
    int t = blockIdx.x * 4 + (threadIdx.x >> 6);   // one wave per token
    const float* xr = x + (size_t)t * HD;
    unsigned short* xbr = xb + (size_t)t * HD;
    float a0=0,a1=0,a2=0,a3=0,a4=0,a5=0,a6=0,a7=0;
    for (int c = lane; c < HD; c += 64) {
        float xv = xr[c];
        xbr[c] = f2bf(xv);
        const float4* g = (const float4*)(gw + (size_t)c * NE);
        float4 g0 = g[0], g1 = g[1];
        a0 += xv * g0.x; a1 += xv * g0.y; a2 += xv * g0.z; a3 += xv * g0.w;
        a4 += xv * g1.x; a5 += xv * g1.y; a6 += xv * g1.z; a7 += xv * g1.w;
    }
#pragma unroll
    for (int off = 32; off > 0; off >>= 1) {
        a0 += __shfl_xor(a0, off); a1 += __shfl_xor(a1, off);
        a2 += __shfl_xor(a2, off); a3 += __shfl_xor(a3, off);
        a4 += __shfl_xor(a4, off); a5 += __shfl_xor(a5, off);
        a6 += __shfl_xor(a6, off); a7 += __shfl_xor(a7, off);
    }
    if (lane == 0) {
        float l[8] = {a0,a1,a2,a3,a4,a5,a6,a7};
        float4 s0 = make_float4(a0,a1,a2,a3);
        float4 s1 = make_float4(a4,a5,a6,a7);
        ((float4*)(logits + (size_t)t * NE))[0] = s0;
        ((float4*)(logits + (size_t)t * NE))[1] = s1;
        int e0 = 0; float v0 = l[0];
#pragma unroll
        for (int e = 1; e < 8; e++) if (l[e] > v0) { v0 = l[e]; e0 = e; }
        int e1 = -1; float v1 = -3.4e38f;
#pragma unroll
        for (int e = 0; e < 8; e++) if (e != e0 && l[e] > v1) { v1 = l[e]; e1 = e; }
        float ex = __expf(v1 - v0);
        float dn = 1.f + ex;
        wts[2*t]   = 1.f / dn;
        wts[2*t+1] = ex / dn;
        eid[2*t]   = e0;
        eid[2*t+1] = e1;
    }
}

// -------- router phase B: build per-expert slot lists via ballot scan (no atomics) --------
// One wave per expert; perm order is ascending slot id (deterministic, gather-friendly).
__global__ void build_perm_kernel(const int* __restrict__ eid, int* __restrict__ perm,
                                  int* __restrict__ counts) {
    int e = blockIdx.x;
    int lane = threadIdx.x;      // 64 threads
    int base = 0;
    int* permE = perm + e * NTOK;
    for (int i0 = 0; i0 < NSLOT; i0 += 64) {
        int s = i0 + lane;
        bool match = (eid[s] == e);
        unsigned long long mask = __ballot(match);
        int pre = __popcll(mask & ((1ULL << lane) - 1ULL));
        if (match) permE[base + pre] = s;
        base += __popcll(mask);
    }
    if (lane == 0) counts[e] = base;
}

// ---------------- gathered GEMM, round-1 proven structure ----------------
// C[M x NTOT] = gather(A)[M x KTOT] * Bt[e]^T, Bt stored [NTOT x KTOT] (B^T).
// Grid: x = n-tile (fast), y = e*64+mtile — round-1 temporal locality.
// G1: A row = xb[slot>>1], epilogue relu->bf16 into h[slot].
// !G1: A row = h[slot], epilogue atomicAdd(out[slot>>1], w[slot]*acc).
template<int KTOT, int NTOT, bool G1>
__global__ __launch_bounds__(256, 2)
void moe_gemm(const unsigned short* __restrict__ A,
              const unsigned short* __restrict__ Bt,
              unsigned short* __restrict__ Hout,
              float* __restrict__ Out,
              const int* __restrict__ counts,
              const int* __restrict__ perm,
              const float* __restrict__ wts) {
    int e = blockIdx.y >> 6;
    int mtile = blockIdx.y & 63;
    int cnt = counts[e];
    if (mtile * 128 >= cnt) return;
    int n0 = blockIdx.x * 128;

    __shared__ unsigned short lds[2 * 128 * 64];   // A tile then B tile, 32 KiB
    __shared__ int slotLds[128];
    __shared__ float wLds[128];

    int tid = threadIdx.x;
    int lane = tid & 63;
    int wv = tid >> 6;
    const int* permE = perm + e * NTOK + mtile * 128;

    if (tid < 128) {
        int s = (mtile * 128 + tid < cnt) ? permE[tid] : -1;
        slotLds[tid] = s;
        if (!G1) wLds[tid] = (s >= 0) ? wts[s] : 0.f;
    }

    // staging row pointers: thread handles rows r_it = it*32 + (tid>>3)
    const unsigned short* aRow[4];
    const unsigned short* bRow[4];
#pragma unroll
    for (int it = 0; it < 4; it++) {
        int r = it * 32 + (tid >> 3);
        int s = (mtile * 128 + r < cnt) ? permE[r] : permE[0];   // clamp to a valid row
        size_t arow = G1 ? (size_t)(s >> 1) : (size_t)s;
        aRow[it] = A + arow * KTOT;
        bRow[it] = Bt + ((size_t)e * NTOT + n0 + r) * KTOT;
    }
    // XOR swizzle: logical k-chunk j of row r lives at physical chunk j^(r&7).
    int koff = ((tid & 7) ^ ((tid >> 3) & 7)) * 8;   // elements
    unsigned short* ldsA = lds;
    unsigned short* ldsB = lds + 128 * 64;
    int wbase = (tid & 192) * 8;                     // wave-uniform LDS chunk base (elems)

    floatx4 acc[4][4];
    floatx4 zero = {0.f, 0.f, 0.f, 0.f};
#pragma unroll
    for (int i = 0; i < 4; i++)
#pragma unroll
        for (int j = 0; j < 4; j++) acc[i][j] = zero;

    int m = lane & 15, quad = lane >> 4;
    int rA = (wv >> 1) * 64 + m;     // + mi*16
    int rB = (wv & 1) * 64 + m;      // + ni*16
    int xs = m & 7;                  // fragment-read swizzle (row&7 == m&7)

    for (int k0 = 0; k0 < KTOT; k0 += 64) {
#pragma unroll
        for (int it = 0; it < 4; it++)
            gload_lds16(aRow[it] + k0 + koff, ldsA + it * 2048 + wbase);
#pragma unroll
        for (int it = 0; it < 4; it++)
            gload_lds16(bRow[it] + k0 + koff, ldsB + it * 2048 + wbase);
        __builtin_amdgcn_s_waitcnt(0);
        __syncthreads();
#pragma unroll
        for (int kk = 0; kk < 2; kk++) {
            bf16x8 af[4], bfr[4];
#pragma unroll
            for (int mi = 0; mi < 4; mi++)
                af[mi] = *(const bf16x8*)(ldsA + (((rA + mi * 16) * 8 + ((kk * 4 + quad) ^ xs)) * 8));
#pragma unroll
            for (int ni = 0; ni < 4; ni++)
                bfr[ni] = *(const bf16x8*)(ldsB + (((rB + ni * 16) * 8 + ((kk * 4 + quad) ^ xs)) * 8));
#pragma unroll
            for (int mi = 0; mi < 4; mi++)
#pragma unroll
                for (int ni = 0; ni < 4; ni++)
                    acc[mi][ni] = __builtin_amdgcn_mfma_f32_16x16x32_bf16(af[mi], bfr[ni], acc[mi][ni], 0, 0, 0);
        }
        __syncthreads();
    }

    // epilogue: C/D layout col = lane&15, row = quad*4 + reg
    int colb = (wv & 1) * 64 + m;          // + ni*16
    int rb = (wv >> 1) * 64 + quad * 4;    // + mi*16 + reg
#pragma unroll
    for (int mi = 0; mi < 4; mi++) {
#pragma unroll
        for (int reg = 0; reg < 4; reg++) {
            int rl = rb + mi * 16 + reg;
            int s = slotLds[rl];
            if (s < 0) continue;
            if (G1) {
                unsigned short* hr = Hout + (size_t)s * NTOT + n0 + colb;
#pragma unroll
                for (int ni = 0; ni < 4; ni++) {
                    float v = acc[mi][ni][reg];
                    hr[ni * 16] = f2bf(v > 0.f ? v : 0.f);
                }
            } else {
                float w = wLds[rl];
                float* orow = Out + (size_t)(s >> 1) * NTOT + n0 + colb;
#pragma unroll
                for (int ni = 0; ni < 4; ni++)
                    atomicAdd(&orow[ni * 16], w * acc[mi][ni][reg]);
            }
        }
    }
}

extern "C" void kernel_launch(void* const* d_in, const int* in_sizes, int n_in,
                              void* d_out, int out_size, void* d_ws, size_t ws_size,
                              hipStream_t stream) {
    (void)in_sizes; (void)n_in; (void)out_size;
    const float* x  = (const float*)d_in[0];
    const float* gw = (const float*)d_in[1];
    const float* w1 = (const float*)d_in[2];
    const float* w2 = (const float*)d_in[3];
    float* out = (float*)d_out;
    float* logits = out + (size_t)NTOK * HD;

    char* ws = (char*)d_ws;
    int*   counts = (int*)ws;                                   // 256 B
    int*   perm   = (int*)(ws + 256);                           // 8*8192*4 = 256 KiB
    float* wts    = (float*)(ws + 256 + 262144);                // 64 KiB
    int*   eid    = (int*)(ws + 256 + 262144 + 65536);          // 64 KiB
    unsigned short* xb    = (unsigned short*)(ws + 458752);                // 16 MiB
    unsigned short* wtbuf = xb + (size_t)NTOK * HD;                        // 64 MiB (w1t, then w2t)
    unsigned short* h     = wtbuf + (size_t)NE * HD * FD;                  // 128 MiB
    size_t needed = 458752 + (size_t)NTOK*HD*2 + (size_t)NE*HD*FD*2 + (size_t)NSLOT*FD*2;
    if (ws_size < needed) return;   // workspace too small — cannot run

    hipMemsetAsync(out, 0, (size_t)NTOK * HD * sizeof(float), stream);

    // w1: [E][H][F] -> w1t [E][F][H]  (rows=H, cols=F)
    transpose_cast_kernel<<<dim3(FD / 64, HD / 64, NE), 256, 0, stream>>>(w1, wtbuf, HD, FD);
    router_kernel<<<NTOK / 4, 256, 0, stream>>>(x, gw, logits, eid, wts, xb);
    build_perm_kernel<<<NE, 64, 0, stream>>>(eid, perm, counts);
    // h[s] = relu(xb[token] @ w1[e]) : K=1024, N=4096 — grid x=n-tile (fast), y=emt
    moe_gemm<HD, FD, true><<<dim3(FD / 128, NE * 64), 256, 0, stream>>>(
        xb, wtbuf, h, nullptr, counts, perm, wts);
    // w2: [E][F][H] -> w2t [E][H][F] (reuse wtbuf; stream order serializes after gemm1)
    transpose_cast_kernel<<<dim3(HD / 64, FD / 64, NE), 256, 0, stream>>>(w2, wtbuf, FD, HD);
    // out[t] += w[s] * (h[s] @ w2[e]) : K=4096, N=1024 — grid x=n-tile (fast), y=emt
    moe_gemm<FD, HD, false><<<dim3(HD / 128, NE * 64), 256, 0, stream>>>(
        h, wtbuf, nullptr, out, counts, perm, wts);
}